// Round 8
// baseline (118.323 us; speedup 1.0000x reference)
//
#include <hip/hip_runtime.h>
#include <hip/hip_bf16.h>

#define D_DIM 1024
#define L_DIM 8
#define T_DIM 2048
#define B_DIM 4
#define TOKS  (B_DIM * T_DIM)                 // 8192
#define OUT_ELEMS ((size_t)TOKS * D_DIM)      // 8388608
#define EPSF 1e-6f

typedef __attribute__((ext_vector_type(8)))  short short8_t;
typedef __attribute__((ext_vector_type(16))) float f32x16_t;
typedef __attribute__((ext_vector_type(4)))  float f32x4_t;
typedef __attribute__((ext_vector_type(2)))  float f32x2_t;

__device__ __forceinline__ float dot4v(const f32x4_t& a, const f32x4_t& b) {
    return a.x * b.x + a.y * b.y + a.z * b.z + a.w * b.w;
}

__device__ __forceinline__ unsigned short f2bf(float f) {
    union { __hip_bfloat16 h; unsigned short u; } x;
    x.h = __float2bfloat16(f);
    return x.u;
}

__device__ __forceinline__ float bf2f(unsigned short u) {
    union { unsigned int i; float f; } x;
    x.i = ((unsigned int)u) << 16;
    return x.f;
}

// ---------------------------------------------------------------------------
// Prep: Wdq[j][k] = Wd[j][k] * qnw[k] as bf16;  Wubf = Wu as bf16.
// ---------------------------------------------------------------------------
__global__ __launch_bounds__(256) void k_prep(const float* __restrict__ Wd,
                                              const float* __restrict__ qnw,
                                              const float* __restrict__ Wu,
                                              unsigned short* __restrict__ Wdq,
                                              unsigned short* __restrict__ Wubf) {
    int i = (blockIdx.x * 256 + threadIdx.x) * 4;
    float4 wd = *(const float4*)(Wd + i);
    float4 nv = *(const float4*)(qnw + (i & (D_DIM - 1)));
    short4 o1 = make_short4((short)f2bf(wd.x * nv.x), (short)f2bf(wd.y * nv.y),
                            (short)f2bf(wd.z * nv.z), (short)f2bf(wd.w * nv.w));
    *(short4*)(Wdq + i) = o1;
    float4 wu = *(const float4*)(Wu + i);
    short4 o2 = make_short4((short)f2bf(wu.x), (short)f2bf(wu.y),
                            (short)f2bf(wu.z), (short)f2bf(wu.w));
    *(short4*)(Wubf + i) = o2;
}

// ---------------------------------------------------------------------------
// Fully fused kernel. 256 blocks x 512 threads; block = 32 tokens.
// Phase A: q tile via MFMA GEMM1/GEMM2 -> qt in LDS (bf16). Also folds the
//          per-token qnorm ssq and the token-gate dot into the single h pass.
// Phase B: per token, stream 8 prev rows (nt f32x2/thread), LDS-transpose
//          reduces for scores, softmax(L), delta, rmsnorm, gated residual.
//          2-deep software pipeline (pA/pB).
// ---------------------------------------------------------------------------
__global__ __launch_bounds__(512) void k_fused(const float* __restrict__ h,
                                               const float* __restrict__ prev,
                                               const unsigned short* __restrict__ Wdq,
                                               const unsigned short* __restrict__ Wubf,
                                               const float* __restrict__ query,
                                               const float* __restrict__ score_w,
                                               const float* __restrict__ out_w,
                                               const float* __restrict__ tg_w,
                                               const float* __restrict__ gate,
                                               const float* __restrict__ tg_b,
                                               float* __restrict__ out,
                                               float* __restrict__ alpha_out) {
    __shared__ __align__(16) char smem[65536];       // c_red | qt overlay
    float (*c_red)[2][16][64] = (float (*)[2][16][64])smem;   // 8 x 2 x 16 x 64
    unsigned short* qt = (unsigned short*)smem;               // 32 x 1024 bf16

    __shared__ float ssq_red[8][32];
    __shared__ float tg_red[8][32];
    __shared__ float scale_sh[32];
    __shared__ float g_sh[32];
    __shared__ float alpha_sh[8][33];
    __shared__ unsigned short r_sw[2048];
    __shared__ float red[16][136];
    __shared__ float red2[136];
    __shared__ float fin[16];

    int tid  = threadIdx.x;
    int w    = tid >> 6;
    int lane = tid & 63;
    int t0   = blockIdx.x * 32;

    // ================= Phase A: GEMM1 =================
    f32x16_t acc0, acc1;
#pragma unroll
    for (int r = 0; r < 16; ++r) { acc0[r] = 0.f; acc1[r] = 0.f; }

    int arow = lane & 31;
    int koff = w * 128 + (lane >> 5) * 8;
    const float* hrow = h + (size_t)(t0 + arow) * D_DIM + koff;
    const unsigned short* b0 = Wdq + (size_t)arow * D_DIM + koff;
    const unsigned short* b1 = Wdq + (size_t)(32 + arow) * D_DIM + koff;
    const float* tgb = tg_w + koff;

    float ssq = 0.f, tgp = 0.f;
#pragma unroll
    for (int s = 0; s < 8; ++s) {
        f32x4_t ha = *(const f32x4_t*)(hrow + s * 16);
        f32x4_t hb = *(const f32x4_t*)(hrow + s * 16 + 4);
        ssq += dot4v(ha, ha) + dot4v(hb, hb);
        f32x4_t ta = *(const f32x4_t*)(tgb + s * 16);
        f32x4_t tb = *(const f32x4_t*)(tgb + s * 16 + 4);
        tgp += dot4v(ha, ta) + dot4v(hb, tb);
        short8_t af;
        af[0] = (short)f2bf(ha.x); af[1] = (short)f2bf(ha.y);
        af[2] = (short)f2bf(ha.z); af[3] = (short)f2bf(ha.w);
        af[4] = (short)f2bf(hb.x); af[5] = (short)f2bf(hb.y);
        af[6] = (short)f2bf(hb.z); af[7] = (short)f2bf(hb.w);
        short8_t bf0 = *(const short8_t*)(b0 + s * 16);
        short8_t bf1 = *(const short8_t*)(b1 + s * 16);
        acc0 = __builtin_amdgcn_mfma_f32_32x32x16_bf16(af, bf0, acc0, 0, 0, 0);
        acc1 = __builtin_amdgcn_mfma_f32_32x32x16_bf16(af, bf1, acc1, 0, 0, 0);
    }

    ssq += __shfl_xor(ssq, 32, 64);
    tgp += __shfl_xor(tgp, 32, 64);
    if (lane < 32) { ssq_red[w][lane] = ssq; tg_red[w][lane] = tgp; }
#pragma unroll
    for (int r = 0; r < 16; ++r) {
        c_red[w][0][r][lane] = acc0[r];
        c_red[w][1][r][lane] = acc1[r];
    }
    __syncthreads();

    if (tid < 32) {
        float s8 = 0.f, t8 = 0.f;
#pragma unroll
        for (int u = 0; u < 8; ++u) { s8 += ssq_red[u][tid]; t8 += tg_red[u][tid]; }
        scale_sh[tid] = rsqrtf(s8 * (1.f / D_DIM) + EPSF);
        g_sh[tid] = gate[0] / (1.f + __expf(-(t8 + tg_b[0])));
    }
    __syncthreads();

    // pack r tile: sum 8 K-partials, scale, bf16, XOR-swizzle store
    for (int idx = tid; idx < 2048; idx += 512) {
        int nj = idx >> 10, rem = idx & 1023, reg = rem >> 6, ln = rem & 63;
        float v = 0.f;
#pragma unroll
        for (int u = 0; u < 8; ++u) v += c_red[u][nj][reg][ln];
        int tk = (reg & 3) + 8 * (reg >> 2) + 4 * (ln >> 5);
        int j  = nj * 32 + (ln & 31);
        v *= scale_sh[tk];
        int byte = (tk * 128 + j * 2) ^ ((tk & 7) << 4);
        r_sw[byte >> 1] = f2bf(v);
    }
    __syncthreads();

    // ================= Phase A: GEMM2 -> qt =================
    short8_t afr[4];
#pragma unroll
    for (int s = 0; s < 4; ++s) {
        int tk = lane & 31;
        int k  = s * 16 + (lane >> 5) * 8;
        int byte = (tk * 128 + k * 2) ^ ((tk & 7) << 4);
        afr[s] = *(const short8_t*)(&r_sw[byte >> 1]);
    }
    __syncthreads();   // c_red dead -> qt overlay safe

#pragma unroll
    for (int i = 0; i < 4; ++i) {
        int n0 = (w * 4 + i) * 32;
        int d  = n0 + (lane & 31);
        f32x16_t c;
#pragma unroll
        for (int r = 0; r < 16; ++r) c[r] = 0.f;
        const unsigned short* bbp = Wubf + (size_t)d * 64 + (lane >> 5) * 8;
#pragma unroll
        for (int s = 0; s < 4; ++s) {
            short8_t bf = *(const short8_t*)(bbp + s * 16);
            c = __builtin_amdgcn_mfma_f32_32x32x16_bf16(afr[s], bf, c, 0, 0, 0);
        }
        float qd  = query[d];
        float swd = score_w[d];
#pragma unroll
        for (int r = 0; r < 16; ++r) {
            int tk = (r & 3) + 8 * (r >> 2) + 4 * (lane >> 5);
            unsigned int v = f2bf((qd + c[r]) * swd);
            unsigned int pv = (unsigned int)__shfl_xor((int)v, 1, 64);
            if ((lane & 1) == 0) {
                unsigned int word = (v & 0xffffu) | (pv << 16);
                *(unsigned int*)&qt[tk * 1024 + d] = word;
            }
        }
    }
    __syncthreads();   // qt ready for phase B

    // ================= Phase B =================
    int tloc0 = t0 & (T_DIM - 1);
    int bb    = t0 >> 11;
    int d0    = tid * 2;
    const float* pb0 = prev + ((size_t)bb * L_DIM * T_DIM + tloc0) * D_DIM + d0;
    const float* hb0 = h + (size_t)t0 * D_DIM + d0;
    float*       ob0 = out + (size_t)t0 * D_DIM + d0;
    f32x2_t ow2 = *(const f32x2_t*)(out_w + d0);

    f32x2_t pA[8], pB[8];
    f32x2_t hA, hB;
    unsigned int qA, qB;

    auto LOADP = [&](int t, f32x2_t (&p)[8], f32x2_t& h2, unsigned int& qr) {
#pragma unroll
        for (int l = 0; l < 8; ++l)
            p[l] = __builtin_nontemporal_load(
                (const f32x2_t*)(pb0 + ((size_t)l * T_DIM + t) * D_DIM));
        h2 = *(const f32x2_t*)(hb0 + (size_t)t * D_DIM);
        qr = *(const unsigned int*)&qt[t * 1024 + d0];
    };

    auto PROCESS = [&](int t, f32x2_t (&p)[8], f32x2_t h2, unsigned int qr) {
        float qlo = bf2f((unsigned short)(qr & 0xffffu));
        float qhi = bf2f((unsigned short)(qr >> 16));
        float ss[8], dt[8];
#pragma unroll
        for (int l = 0; l < 8; ++l) {
            ss[l] = p[l].x * p[l].x + p[l].y * p[l].y;
            dt[l] = p[l].x * qlo + p[l].y * qhi;
        }
#pragma unroll
        for (int l = 0; l < 8; ++l) {
            ss[l] += __shfl_xor(ss[l], 1, 64); ss[l] += __shfl_xor(ss[l], 2, 64);
            dt[l] += __shfl_xor(dt[l], 1, 64); dt[l] += __shfl_xor(dt[l], 2, 64);
        }
        if ((tid & 3) == 0) {
            int e = tid >> 2;
#pragma unroll
            for (int l = 0; l < 8; ++l) { red[l][e] = ss[l]; red[l + 8][e] = dt[l]; }
        }
        __syncthreads();
        {
            int v = tid >> 5, e = tid & 31;
            float s = red[v][e] + red[v][e + 32] + red[v][e + 64] + red[v][e + 96];
            s += __shfl_xor(s, 1, 64);  s += __shfl_xor(s, 2, 64);
            s += __shfl_xor(s, 4, 64);  s += __shfl_xor(s, 8, 64);
            s += __shfl_xor(s, 16, 64);
            if (e == 0) fin[v] = s;
        }
        __syncthreads();
        float al[8];
        float mx = -1e30f;
#pragma unroll
        for (int l = 0; l < 8; ++l) {
            al[l] = fin[l + 8] * rsqrtf(fin[l] * (1.f / D_DIM) + EPSF);
            mx = fmaxf(mx, al[l]);
        }
        float asum = 0.f;
#pragma unroll
        for (int l = 0; l < 8; ++l) { al[l] = __expf(al[l] - mx); asum += al[l]; }
        float inv = 1.f / asum;
        float dx = 0.f, dy = 0.f;
#pragma unroll
        for (int l = 0; l < 8; ++l) { al[l] *= inv; dx += al[l] * p[l].x; dy += al[l] * p[l].y; }
#pragma unroll
        for (int l = 0; l < 8; ++l) if (tid == l) alpha_sh[l][t] = al[l];
        float dsp = dx * dx + dy * dy;
        dsp += __shfl_xor(dsp, 1, 64); dsp += __shfl_xor(dsp, 2, 64);
        if ((tid & 3) == 0) red2[tid >> 2] = dsp;
        __syncthreads();
        {
            int e = tid & 31;
            float s = red2[e] + red2[e + 32] + red2[e + 64] + red2[e + 96];
            s += __shfl_xor(s, 1, 64);  s += __shfl_xor(s, 2, 64);
            s += __shfl_xor(s, 4, 64);  s += __shfl_xor(s, 8, 64);
            s += __shfl_xor(s, 16, 64);
            float dscale = rsqrtf(s * (1.f / D_DIM) + EPSF);
            float g = g_sh[t];
            f32x2_t o;
            o.x = h2.x + g * dx * dscale * ow2.x;
            o.y = h2.y + g * dy * dscale * ow2.y;
            __builtin_nontemporal_store(o, (f32x2_t*)(ob0 + (size_t)t * D_DIM));
        }
    };

    LOADP(0, pA, hA, qA);
#pragma unroll 1
    for (int t = 0; t < 32; t += 2) {
        if (t + 1 < 32) LOADP(t + 1, pB, hB, qB);
        PROCESS(t, pA, hA, qA);
        if (t + 2 < 32) LOADP(t + 2, pA, hA, qA);
        PROCESS(t + 1, pB, hB, qB);
    }

    __syncthreads();
    if (tid < 64) {
        int l = tid >> 3, c = (tid & 7) * 4;
        float4 v;
        v.x = alpha_sh[l][c];     v.y = alpha_sh[l][c + 1];
        v.z = alpha_sh[l][c + 2]; v.w = alpha_sh[l][c + 3];
        *(float4*)(alpha_out + (size_t)bb * (L_DIM * T_DIM) + (size_t)l * T_DIM + tloc0 + c) = v;
    }
}

extern "C" void kernel_launch(void* const* d_in, const int* in_sizes, int n_in,
                              void* d_out, int out_size, void* d_ws, size_t ws_size,
                              hipStream_t stream) {
    (void)in_sizes; (void)n_in; (void)out_size; (void)ws_size;
    const float* h       = (const float*)d_in[0];
    const float* prev    = (const float*)d_in[1];
    const float* query   = (const float*)d_in[2];
    const float* gate    = (const float*)d_in[3];
    const float* score_w = (const float*)d_in[4];
    const float* out_w   = (const float*)d_in[5];
    const float* qnw     = (const float*)d_in[6];
    const float* Wd      = (const float*)d_in[7];
    const float* Wu      = (const float*)d_in[8];
    const float* tg_w    = (const float*)d_in[9];
    const float* tg_b    = (const float*)d_in[10];

    float* out   = (float*)d_out;
    float* alpha = out + OUT_ELEMS;

    unsigned short* Wdq  = (unsigned short*)d_ws;                 // 128 KB
    unsigned short* Wubf = Wdq + (size_t)64 * D_DIM;              // 128 KB

    k_prep<<<64, 256, 0, stream>>>(Wd, qnw, Wu, Wdq, Wubf);
    k_fused<<<256, 512, 0, stream>>>(h, prev, Wdq, Wubf, query, score_w, out_w,
                                     tg_w, gate, tg_b, out, alpha);
}

// Round 9
// 87.103 us; speedup vs baseline: 1.3584x; 1.3584x over previous
//
#include <hip/hip_runtime.h>
#include <hip/hip_bf16.h>

#define D_DIM 1024
#define L_DIM 8
#define T_DIM 2048
#define B_DIM 4
#define TOKS  (B_DIM * T_DIM)                 // 8192
#define OUT_ELEMS ((size_t)TOKS * D_DIM)      // 8388608
#define EPSF 1e-6f

typedef __attribute__((ext_vector_type(8)))  short short8_t;
typedef __attribute__((ext_vector_type(16))) float f32x16_t;
typedef __attribute__((ext_vector_type(4)))  float f32x4_t;

__device__ __forceinline__ float dot4v(const f32x4_t& a, const f32x4_t& b) {
    return a.x * b.x + a.y * b.y + a.z * b.z + a.w * b.w;
}

__device__ __forceinline__ unsigned short f2bf(float f) {
    union { __hip_bfloat16 h; unsigned short u; } x;
    x.h = __float2bfloat16(f);
    return x.u;
}

__device__ __forceinline__ float bf2f(unsigned short u) {
    union { unsigned int i; float f; } x;
    x.i = ((unsigned int)u) << 16;
    return x.f;
}

// ---------------------------------------------------------------------------
// Prep: Wdq[j][k] = Wd[j][k] * qnw[k] as bf16;  Wubf = Wu as bf16.
// ---------------------------------------------------------------------------
__global__ __launch_bounds__(256) void k_prep(const float* __restrict__ Wd,
                                              const float* __restrict__ qnw,
                                              const float* __restrict__ Wu,
                                              unsigned short* __restrict__ Wdq,
                                              unsigned short* __restrict__ Wubf) {
    int i = (blockIdx.x * 256 + threadIdx.x) * 4;
    float4 wd = *(const float4*)(Wd + i);
    float4 nv = *(const float4*)(qnw + (i & (D_DIM - 1)));
    short4 o1 = make_short4((short)f2bf(wd.x * nv.x), (short)f2bf(wd.y * nv.y),
                            (short)f2bf(wd.z * nv.z), (short)f2bf(wd.w * nv.w));
    *(short4*)(Wdq + i) = o1;
    float4 wu = *(const float4*)(Wu + i);
    short4 o2 = make_short4((short)f2bf(wu.x), (short)f2bf(wu.y),
                            (short)f2bf(wu.z), (short)f2bf(wu.w));
    *(short4*)(Wubf + i) = o2;
}

// ---------------------------------------------------------------------------
// Fused q kernel: 32 tokens/block, 512 thr, MFMA GEMMs; qs out via LDS
// transpose -> coalesced 16B stores.  (verified R6 version)
// ---------------------------------------------------------------------------
#define QT_STRIDE 1048
__global__ __launch_bounds__(512) void k_q(const float* __restrict__ h,
                                           const unsigned short* __restrict__ Wdq,
                                           const unsigned short* __restrict__ Wubf,
                                           const float* __restrict__ query,
                                           const float* __restrict__ score_w,
                                           unsigned short* __restrict__ qs) {
    __shared__ __align__(16) char smem[70784];
    float (*c_red)[2][16][64] = (float (*)[2][16][64])smem;               // 64 KB
    float (*ssq_red)[32]      = (float (*)[32])(smem + 65536);            // 1 KB
    float* scale_sh           = (float*)(smem + 66560);                   // 128 B
    unsigned short* r_sw      = (unsigned short*)(smem + 66688);          // 4 KB
    unsigned short* qt        = (unsigned short*)smem;                    // overlay

    int tid  = threadIdx.x;
    int w    = tid >> 6;
    int lane = tid & 63;
    int t0   = blockIdx.x * 32;

    f32x16_t acc0, acc1;
#pragma unroll
    for (int r = 0; r < 16; ++r) { acc0[r] = 0.f; acc1[r] = 0.f; }

    int arow = lane & 31;
    int koff = w * 128 + (lane >> 5) * 8;
    const float* hrow = h + (size_t)(t0 + arow) * D_DIM + koff;
    const unsigned short* b0 = Wdq + (size_t)arow * D_DIM + koff;
    const unsigned short* b1 = Wdq + (size_t)(32 + arow) * D_DIM + koff;

    float ssq = 0.f;
#pragma unroll
    for (int s = 0; s < 8; ++s) {
        f32x4_t ha = *(const f32x4_t*)(hrow + s * 16);
        f32x4_t hb = *(const f32x4_t*)(hrow + s * 16 + 4);
        ssq += dot4v(ha, ha) + dot4v(hb, hb);
        short8_t af;
        af[0] = (short)f2bf(ha.x); af[1] = (short)f2bf(ha.y);
        af[2] = (short)f2bf(ha.z); af[3] = (short)f2bf(ha.w);
        af[4] = (short)f2bf(hb.x); af[5] = (short)f2bf(hb.y);
        af[6] = (short)f2bf(hb.z); af[7] = (short)f2bf(hb.w);
        short8_t bf0 = *(const short8_t*)(b0 + s * 16);
        short8_t bf1 = *(const short8_t*)(b1 + s * 16);
        acc0 = __builtin_amdgcn_mfma_f32_32x32x16_bf16(af, bf0, acc0, 0, 0, 0);
        acc1 = __builtin_amdgcn_mfma_f32_32x32x16_bf16(af, bf1, acc1, 0, 0, 0);
    }

    ssq += __shfl_xor(ssq, 32, 64);
    if (lane < 32) ssq_red[w][lane] = ssq;
#pragma unroll
    for (int r = 0; r < 16; ++r) {
        c_red[w][0][r][lane] = acc0[r];
        c_red[w][1][r][lane] = acc1[r];
    }
    __syncthreads();

    if (tid < 32) {
        float s8 = 0.f;
#pragma unroll
        for (int u = 0; u < 8; ++u) s8 += ssq_red[u][tid];
        scale_sh[tid] = rsqrtf(s8 * (1.f / D_DIM) + EPSF);
    }
    __syncthreads();

    for (int idx = tid; idx < 2048; idx += 512) {
        int nj = idx >> 10, rem = idx & 1023, reg = rem >> 6, ln = rem & 63;
        float v = 0.f;
#pragma unroll
        for (int u = 0; u < 8; ++u) v += c_red[u][nj][reg][ln];
        int tk = (reg & 3) + 8 * (reg >> 2) + 4 * (ln >> 5);
        int j  = nj * 32 + (ln & 31);
        v *= scale_sh[tk];
        int byte = (tk * 128 + j * 2) ^ ((tk & 7) << 4);
        r_sw[byte >> 1] = f2bf(v);
    }
    __syncthreads();

    short8_t afr[4];
#pragma unroll
    for (int s = 0; s < 4; ++s) {
        int tk = lane & 31;
        int k  = s * 16 + (lane >> 5) * 8;
        int byte = (tk * 128 + k * 2) ^ ((tk & 7) << 4);
        afr[s] = *(const short8_t*)(&r_sw[byte >> 1]);
    }
    __syncthreads();

#pragma unroll
    for (int i = 0; i < 4; ++i) {
        int n0 = (w * 4 + i) * 32;
        int d  = n0 + (lane & 31);
        f32x16_t c;
#pragma unroll
        for (int r = 0; r < 16; ++r) c[r] = 0.f;
        const unsigned short* bbp = Wubf + (size_t)d * 64 + (lane >> 5) * 8;
#pragma unroll
        for (int s = 0; s < 4; ++s) {
            short8_t bf = *(const short8_t*)(bbp + s * 16);
            c = __builtin_amdgcn_mfma_f32_32x32x16_bf16(afr[s], bf, c, 0, 0, 0);
        }
        float qd  = query[d];
        float swd = score_w[d];
#pragma unroll
        for (int r = 0; r < 16; ++r) {
            int tk = (r & 3) + 8 * (r >> 2) + 4 * (lane >> 5);
            unsigned int v = f2bf((qd + c[r]) * swd);
            unsigned int pv = (unsigned int)__shfl_xor((int)v, 1, 64);
            if ((lane & 1) == 0) {
                unsigned int word = (v & 0xffffu) | (pv << 16);
                *(unsigned int*)&qt[tk * QT_STRIDE + d] = word;
            }
        }
    }
    __syncthreads();

#pragma unroll
    for (int j = 0; j < 8; ++j) {
        int row   = tid >> 4;
        int chunk = (tid & 15) + j * 16;
        short8_t v = *(const short8_t*)&qt[row * QT_STRIDE + chunk * 8];
        *(short8_t*)(qs + (size_t)(t0 + row) * D_DIM + chunk * 8) = v;
    }
}

// ---------------------------------------------------------------------------
// Main kernel: ONE WAVE PER TOKEN. Zero barriers, zero LDS. All 8 prev rows
// in registers (lane = 4 x float4 columns); 16 ILP-parallel butterflies.
// ---------------------------------------------------------------------------
__global__ __launch_bounds__(256) void k_main(const float* __restrict__ h,
                                              const float* __restrict__ prev,
                                              const unsigned short* __restrict__ qs,
                                              const float* __restrict__ out_w,
                                              const float* __restrict__ tg_w,
                                              const float* __restrict__ gate,
                                              const float* __restrict__ tg_b,
                                              float* __restrict__ out,
                                              float* __restrict__ alpha_out) {
    int lane = threadIdx.x & 63;
    int tok  = (blockIdx.x << 2) + (threadIdx.x >> 6);
    int b    = tok >> 11;
    int t    = tok & (T_DIM - 1);

    // stream 8 prev rows into registers: 32 x 1KB-per-wave loads, row-major
    const float* pb = prev + ((size_t)(b * L_DIM) * T_DIM + t) * D_DIM + lane * 4;
    f32x4_t p[L_DIM][4];
#pragma unroll
    for (int l = 0; l < L_DIM; ++l)
#pragma unroll
        for (int c = 0; c < 4; ++c)
            p[l][c] = __builtin_nontemporal_load(
                (const f32x4_t*)(pb + (size_t)l * T_DIM * D_DIM + c * 256));

    const float* hb = h + (size_t)tok * D_DIM + lane * 4;
    f32x4_t h4[4], qv[4];
#pragma unroll
    for (int c = 0; c < 4; ++c) h4[c] = *(const f32x4_t*)(hb + c * 256);
#pragma unroll
    for (int c = 0; c < 4; ++c) {
        short4 qr = *(const short4*)(qs + (size_t)tok * D_DIM + c * 256 + lane * 4);
        qv[c].x = bf2f((unsigned short)qr.x);
        qv[c].y = bf2f((unsigned short)qr.y);
        qv[c].z = bf2f((unsigned short)qr.z);
        qv[c].w = bf2f((unsigned short)qr.w);
    }

    // token-gate partial
    float tgp = 0.f;
#pragma unroll
    for (int c = 0; c < 4; ++c) {
        f32x4_t tw = *(const f32x4_t*)(tg_w + c * 256 + lane * 4);
        tgp += dot4v(h4[c], tw);
    }

    float ss[L_DIM], dt[L_DIM];
#pragma unroll
    for (int l = 0; l < L_DIM; ++l) {
        float s = 0.f, d = 0.f;
#pragma unroll
        for (int c = 0; c < 4; ++c) {
            s += dot4v(p[l][c], p[l][c]);
            d += dot4v(p[l][c], qv[c]);
        }
        ss[l] = s; dt[l] = d;
    }

    // 17 independent butterflies (6 levels), no LDS, no barriers
#pragma unroll
    for (int off = 32; off; off >>= 1) {
#pragma unroll
        for (int l = 0; l < L_DIM; ++l) {
            ss[l] += __shfl_xor(ss[l], off, 64);
            dt[l] += __shfl_xor(dt[l], off, 64);
        }
        tgp += __shfl_xor(tgp, off, 64);
    }

    float al[L_DIM], mx = -1e30f;
#pragma unroll
    for (int l = 0; l < L_DIM; ++l) {
        al[l] = dt[l] * rsqrtf(ss[l] * (1.f / D_DIM) + EPSF);
        mx = fmaxf(mx, al[l]);
    }
    float asum = 0.f;
#pragma unroll
    for (int l = 0; l < L_DIM; ++l) { al[l] = __expf(al[l] - mx); asum += al[l]; }
    float inv = 1.f / asum;
#pragma unroll
    for (int l = 0; l < L_DIM; ++l) al[l] *= inv;

    float g = gate[0] / (1.f + __expf(-(tgp + tg_b[0])));

    f32x4_t dl[4];
#pragma unroll
    for (int c = 0; c < 4; ++c) { dl[c].x = 0.f; dl[c].y = 0.f; dl[c].z = 0.f; dl[c].w = 0.f; }
#pragma unroll
    for (int l = 0; l < L_DIM; ++l)
#pragma unroll
        for (int c = 0; c < 4; ++c) {
            dl[c].x += al[l] * p[l][c].x;
            dl[c].y += al[l] * p[l][c].y;
            dl[c].z += al[l] * p[l][c].z;
            dl[c].w += al[l] * p[l][c].w;
        }

    float dss = 0.f;
#pragma unroll
    for (int c = 0; c < 4; ++c) dss += dot4v(dl[c], dl[c]);
#pragma unroll
    for (int off = 32; off; off >>= 1) dss += __shfl_xor(dss, off, 64);
    float dscale = rsqrtf(dss * (1.f / D_DIM) + EPSF);

    float* ob = out + (size_t)tok * D_DIM + lane * 4;
#pragma unroll
    for (int c = 0; c < 4; ++c) {
        f32x4_t ow = *(const f32x4_t*)(out_w + c * 256 + lane * 4);
        f32x4_t o;
        o.x = h4[c].x + g * dl[c].x * dscale * ow.x;
        o.y = h4[c].y + g * dl[c].y * dscale * ow.y;
        o.z = h4[c].z + g * dl[c].z * dscale * ow.z;
        o.w = h4[c].w + g * dl[c].w * dscale * ow.w;
        __builtin_nontemporal_store(o, (f32x4_t*)(ob + c * 256));
    }

    if (lane < L_DIM)
        alpha_out[(size_t)b * (L_DIM * T_DIM) + (size_t)lane * T_DIM + t] = al[lane];
}

extern "C" void kernel_launch(void* const* d_in, const int* in_sizes, int n_in,
                              void* d_out, int out_size, void* d_ws, size_t ws_size,
                              hipStream_t stream) {
    (void)in_sizes; (void)n_in; (void)out_size; (void)ws_size;
    const float* h       = (const float*)d_in[0];
    const float* prev    = (const float*)d_in[1];
    const float* query   = (const float*)d_in[2];
    const float* gate    = (const float*)d_in[3];
    const float* score_w = (const float*)d_in[4];
    const float* out_w   = (const float*)d_in[5];
    const float* qnw     = (const float*)d_in[6];
    const float* Wd      = (const float*)d_in[7];
    const float* Wu      = (const float*)d_in[8];
    const float* tg_w    = (const float*)d_in[9];
    const float* tg_b    = (const float*)d_in[10];

    float* out   = (float*)d_out;
    float* alpha = out + OUT_ELEMS;

    unsigned short* qsbuf = (unsigned short*)d_ws;                 // 16 MB
    unsigned short* Wdq   = qsbuf + OUT_ELEMS;                     // 128 KB
    unsigned short* Wubf  = Wdq + (size_t)64 * D_DIM;              // 128 KB

    k_prep<<<64, 256, 0, stream>>>(Wd, qnw, Wu, Wdq, Wubf);
    k_q<<<TOKS / 32, 512, 0, stream>>>(h, Wdq, Wubf, query, score_w, qsbuf);
    k_main<<<TOKS / 4, 256, 0, stream>>>(h, prev, qsbuf, out_w, tg_w, gate, tg_b, out, alpha);
}

// Round 10
// 84.302 us; speedup vs baseline: 1.4036x; 1.0332x over previous
//
#include <hip/hip_runtime.h>
#include <hip/hip_bf16.h>

#define D_DIM 1024
#define L_DIM 8
#define T_DIM 2048
#define B_DIM 4
#define TOKS  (B_DIM * T_DIM)                 // 8192
#define OUT_ELEMS ((size_t)TOKS * D_DIM)      // 8388608
#define EPSF 1e-6f

typedef __attribute__((ext_vector_type(8)))  short short8_t;
typedef __attribute__((ext_vector_type(16))) float f32x16_t;
typedef __attribute__((ext_vector_type(4)))  float f32x4_t;

__device__ __forceinline__ float dot4v(const f32x4_t& a, const f32x4_t& b) {
    return a.x * b.x + a.y * b.y + a.z * b.z + a.w * b.w;
}

__device__ __forceinline__ unsigned short f2bf(float f) {
    union { __hip_bfloat16 h; unsigned short u; } x;
    x.h = __float2bfloat16(f);
    return x.u;
}

__device__ __forceinline__ float bf2f(unsigned short u) {
    union { unsigned int i; float f; } x;
    x.i = ((unsigned int)u) << 16;
    return x.f;
}

// ---------------------------------------------------------------------------
// Single fused kernel. 256 blocks x 512 threads; block = 32 tokens.
// Phase A (one barrier chain): q tile via MFMA GEMM1/GEMM2 -> qt LDS (bf16).
//   Weights read as f32 from L2 and converted inline (no prep kernel).
// Phase B (ZERO barriers): wave-per-token x4; prev rows in registers,
//   butterflies in-wave, softmax, delta, rmsnorm, gated residual, nt store.
// ---------------------------------------------------------------------------
__global__ __launch_bounds__(512) void k_all(const float* __restrict__ h,
                                             const float* __restrict__ prev,
                                             const float* __restrict__ query,
                                             const float* __restrict__ score_w,
                                             const float* __restrict__ out_w,
                                             const float* __restrict__ tg_w,
                                             const float* __restrict__ gate,
                                             const float* __restrict__ tg_b,
                                             const float* __restrict__ qnw,
                                             const float* __restrict__ Wd,
                                             const float* __restrict__ Wu,
                                             float* __restrict__ out,
                                             float* __restrict__ alpha_out) {
    __shared__ __align__(16) char smem[65536];                 // c_red | qt overlay
    float (*c_red)[2][16][64] = (float (*)[2][16][64])smem;    // 64 KB
    unsigned short* qt = (unsigned short*)smem;                // 32 x 1024 bf16

    __shared__ float ssq_red[8][32];
    __shared__ float scale_sh[32];
    __shared__ unsigned short r_sw[2048];

    int tid  = threadIdx.x;
    int w    = tid >> 6;
    int lane = tid & 63;
    int t0   = blockIdx.x * 32;

    // ================= Phase A: GEMM1 =================
    f32x16_t acc0, acc1;
#pragma unroll
    for (int r = 0; r < 16; ++r) { acc0[r] = 0.f; acc1[r] = 0.f; }

    int arow = lane & 31;
    int koff = w * 128 + (lane >> 5) * 8;
    const float* hrow = h + (size_t)(t0 + arow) * D_DIM + koff;
    const float* w0r  = Wd + (size_t)arow * D_DIM + koff;
    const float* w1r  = Wd + (size_t)(32 + arow) * D_DIM + koff;
    const float* nr   = qnw + koff;

    float ssq = 0.f;
#pragma unroll
    for (int s = 0; s < 8; ++s) {
        f32x4_t ha = *(const f32x4_t*)(hrow + s * 16);
        f32x4_t hb = *(const f32x4_t*)(hrow + s * 16 + 4);
        ssq += dot4v(ha, ha) + dot4v(hb, hb);
        short8_t af;
        af[0] = (short)f2bf(ha.x); af[1] = (short)f2bf(ha.y);
        af[2] = (short)f2bf(ha.z); af[3] = (short)f2bf(ha.w);
        af[4] = (short)f2bf(hb.x); af[5] = (short)f2bf(hb.y);
        af[6] = (short)f2bf(hb.z); af[7] = (short)f2bf(hb.w);
        f32x4_t na = *(const f32x4_t*)(nr + s * 16);
        f32x4_t nb = *(const f32x4_t*)(nr + s * 16 + 4);
        f32x4_t wa = *(const f32x4_t*)(w0r + s * 16);
        f32x4_t wb = *(const f32x4_t*)(w0r + s * 16 + 4);
        short8_t bf0;
        bf0[0] = (short)f2bf(wa.x * na.x); bf0[1] = (short)f2bf(wa.y * na.y);
        bf0[2] = (short)f2bf(wa.z * na.z); bf0[3] = (short)f2bf(wa.w * na.w);
        bf0[4] = (short)f2bf(wb.x * nb.x); bf0[5] = (short)f2bf(wb.y * nb.y);
        bf0[6] = (short)f2bf(wb.z * nb.z); bf0[7] = (short)f2bf(wb.w * nb.w);
        f32x4_t va = *(const f32x4_t*)(w1r + s * 16);
        f32x4_t vb = *(const f32x4_t*)(w1r + s * 16 + 4);
        short8_t bf1;
        bf1[0] = (short)f2bf(va.x * na.x); bf1[1] = (short)f2bf(va.y * na.y);
        bf1[2] = (short)f2bf(va.z * na.z); bf1[3] = (short)f2bf(va.w * na.w);
        bf1[4] = (short)f2bf(vb.x * nb.x); bf1[5] = (short)f2bf(vb.y * nb.y);
        bf1[6] = (short)f2bf(vb.z * nb.z); bf1[7] = (short)f2bf(vb.w * nb.w);
        acc0 = __builtin_amdgcn_mfma_f32_32x32x16_bf16(af, bf0, acc0, 0, 0, 0);
        acc1 = __builtin_amdgcn_mfma_f32_32x32x16_bf16(af, bf1, acc1, 0, 0, 0);
    }

    ssq += __shfl_xor(ssq, 32, 64);
    if (lane < 32) ssq_red[w][lane] = ssq;
#pragma unroll
    for (int r = 0; r < 16; ++r) {
        c_red[w][0][r][lane] = acc0[r];
        c_red[w][1][r][lane] = acc1[r];
    }
    __syncthreads();

    if (tid < 32) {
        float s8 = 0.f;
#pragma unroll
        for (int u = 0; u < 8; ++u) s8 += ssq_red[u][tid];
        scale_sh[tid] = rsqrtf(s8 * (1.f / D_DIM) + EPSF);
    }
    __syncthreads();

    // pack r tile: sum 8 K-partials, scale, bf16, XOR-swizzle store
    for (int idx = tid; idx < 2048; idx += 512) {
        int nj = idx >> 10, rem = idx & 1023, reg = rem >> 6, ln = rem & 63;
        float v = 0.f;
#pragma unroll
        for (int u = 0; u < 8; ++u) v += c_red[u][nj][reg][ln];
        int tk = (reg & 3) + 8 * (reg >> 2) + 4 * (ln >> 5);
        int j  = nj * 32 + (ln & 31);
        v *= scale_sh[tk];
        int byte = (tk * 128 + j * 2) ^ ((tk & 7) << 4);
        r_sw[byte >> 1] = f2bf(v);
    }
    __syncthreads();

    // ================= Phase A: GEMM2 -> qt =================
    short8_t afr[4];
#pragma unroll
    for (int s = 0; s < 4; ++s) {
        int tk = lane & 31;
        int k  = s * 16 + (lane >> 5) * 8;
        int byte = (tk * 128 + k * 2) ^ ((tk & 7) << 4);
        afr[s] = *(const short8_t*)(&r_sw[byte >> 1]);
    }
    __syncthreads();   // c_red dead -> qt overlay safe

#pragma unroll
    for (int i = 0; i < 4; ++i) {
        int n0 = (w * 4 + i) * 32;
        int d  = n0 + (lane & 31);
        f32x16_t c;
#pragma unroll
        for (int r = 0; r < 16; ++r) c[r] = 0.f;
        const float* wup = Wu + (size_t)d * 64 + (lane >> 5) * 8;
#pragma unroll
        for (int s = 0; s < 4; ++s) {
            f32x4_t ua = *(const f32x4_t*)(wup + s * 16);
            f32x4_t ub = *(const f32x4_t*)(wup + s * 16 + 4);
            short8_t bf;
            bf[0] = (short)f2bf(ua.x); bf[1] = (short)f2bf(ua.y);
            bf[2] = (short)f2bf(ua.z); bf[3] = (short)f2bf(ua.w);
            bf[4] = (short)f2bf(ub.x); bf[5] = (short)f2bf(ub.y);
            bf[6] = (short)f2bf(ub.z); bf[7] = (short)f2bf(ub.w);
            c = __builtin_amdgcn_mfma_f32_32x32x16_bf16(afr[s], bf, c, 0, 0, 0);
        }
        float qd  = query[d];
        float swd = score_w[d];
#pragma unroll
        for (int r = 0; r < 16; ++r) {
            int tk = (r & 3) + 8 * (r >> 2) + 4 * (lane >> 5);
            unsigned int v = f2bf((qd + c[r]) * swd);
            unsigned int pv = (unsigned int)__shfl_xor((int)v, 1, 64);
            if ((lane & 1) == 0) {
                unsigned int word = (v & 0xffffu) | (pv << 16);
                *(unsigned int*)&qt[tk * 1024 + d] = word;
            }
        }
    }
    __syncthreads();   // qt ready; NO MORE BARRIERS below

    // ================= Phase B: wave-per-token, zero barriers =============
    int bb    = t0 >> 11;
    int tloc0 = t0 & (T_DIM - 1);

#pragma unroll 1
    for (int i = 0; i < 4; ++i) {
        int tt  = w * 4 + i;              // local token 0..31
        int tok = t0 + tt;
        int t   = tloc0 + tt;

        const float* pb = prev + ((size_t)(bb * L_DIM) * T_DIM + t) * D_DIM + lane * 4;
        f32x4_t p[L_DIM][4];
#pragma unroll
        for (int l = 0; l < L_DIM; ++l)
#pragma unroll
            for (int c = 0; c < 4; ++c)
                p[l][c] = __builtin_nontemporal_load(
                    (const f32x4_t*)(pb + (size_t)l * T_DIM * D_DIM + c * 256));

        const float* hb = h + (size_t)tok * D_DIM + lane * 4;
        f32x4_t h4[4], qv[4];
#pragma unroll
        for (int c = 0; c < 4; ++c) h4[c] = *(const f32x4_t*)(hb + c * 256);
#pragma unroll
        for (int c = 0; c < 4; ++c) {
            short4 qr = *(const short4*)&qt[tt * 1024 + c * 256 + lane * 4];
            qv[c].x = bf2f((unsigned short)qr.x);
            qv[c].y = bf2f((unsigned short)qr.y);
            qv[c].z = bf2f((unsigned short)qr.z);
            qv[c].w = bf2f((unsigned short)qr.w);
        }

        float tgp = 0.f;
#pragma unroll
        for (int c = 0; c < 4; ++c) {
            f32x4_t tw = *(const f32x4_t*)(tg_w + c * 256 + lane * 4);
            tgp += dot4v(h4[c], tw);
        }

        float ss[L_DIM], dt[L_DIM];
#pragma unroll
        for (int l = 0; l < L_DIM; ++l) {
            float s = 0.f, d = 0.f;
#pragma unroll
            for (int c = 0; c < 4; ++c) {
                s += dot4v(p[l][c], p[l][c]);
                d += dot4v(p[l][c], qv[c]);
            }
            ss[l] = s; dt[l] = d;
        }

#pragma unroll
        for (int off = 32; off; off >>= 1) {
#pragma unroll
            for (int l = 0; l < L_DIM; ++l) {
                ss[l] += __shfl_xor(ss[l], off, 64);
                dt[l] += __shfl_xor(dt[l], off, 64);
            }
            tgp += __shfl_xor(tgp, off, 64);
        }

        float al[L_DIM], mx = -1e30f;
#pragma unroll
        for (int l = 0; l < L_DIM; ++l) {
            al[l] = dt[l] * rsqrtf(ss[l] * (1.f / D_DIM) + EPSF);
            mx = fmaxf(mx, al[l]);
        }
        float asum = 0.f;
#pragma unroll
        for (int l = 0; l < L_DIM; ++l) { al[l] = __expf(al[l] - mx); asum += al[l]; }
        float inv = 1.f / asum;
#pragma unroll
        for (int l = 0; l < L_DIM; ++l) al[l] *= inv;

        float g = gate[0] / (1.f + __expf(-(tgp + tg_b[0])));

        f32x4_t dl[4];
#pragma unroll
        for (int c = 0; c < 4; ++c) { dl[c].x = 0.f; dl[c].y = 0.f; dl[c].z = 0.f; dl[c].w = 0.f; }
#pragma unroll
        for (int l = 0; l < L_DIM; ++l)
#pragma unroll
            for (int c = 0; c < 4; ++c) {
                dl[c].x += al[l] * p[l][c].x;
                dl[c].y += al[l] * p[l][c].y;
                dl[c].z += al[l] * p[l][c].z;
                dl[c].w += al[l] * p[l][c].w;
            }

        float dss = 0.f;
#pragma unroll
        for (int c = 0; c < 4; ++c) dss += dot4v(dl[c], dl[c]);
#pragma unroll
        for (int off = 32; off; off >>= 1) dss += __shfl_xor(dss, off, 64);
        float dscale = rsqrtf(dss * (1.f / D_DIM) + EPSF);

        float* ob = out + (size_t)tok * D_DIM + lane * 4;
#pragma unroll
        for (int c = 0; c < 4; ++c) {
            f32x4_t ow = *(const f32x4_t*)(out_w + c * 256 + lane * 4);
            f32x4_t o;
            o.x = h4[c].x + g * dl[c].x * dscale * ow.x;
            o.y = h4[c].y + g * dl[c].y * dscale * ow.y;
            o.z = h4[c].z + g * dl[c].z * dscale * ow.z;
            o.w = h4[c].w + g * dl[c].w * dscale * ow.w;
            __builtin_nontemporal_store(o, (f32x4_t*)(ob + c * 256));
        }

        if (lane < L_DIM)
            alpha_out[(size_t)bb * (L_DIM * T_DIM) + (size_t)lane * T_DIM + t] = al[lane];
    }
}

extern "C" void kernel_launch(void* const* d_in, const int* in_sizes, int n_in,
                              void* d_out, int out_size, void* d_ws, size_t ws_size,
                              hipStream_t stream) {
    (void)in_sizes; (void)n_in; (void)out_size; (void)d_ws; (void)ws_size;
    const float* h       = (const float*)d_in[0];
    const float* prev    = (const float*)d_in[1];
    const float* query   = (const float*)d_in[2];
    const float* gate    = (const float*)d_in[3];
    const float* score_w = (const float*)d_in[4];
    const float* out_w   = (const float*)d_in[5];
    const float* qnw     = (const float*)d_in[6];
    const float* Wd      = (const float*)d_in[7];
    const float* Wu      = (const float*)d_in[8];
    const float* tg_w    = (const float*)d_in[9];
    const float* tg_b    = (const float*)d_in[10];

    float* out   = (float*)d_out;
    float* alpha = out + OUT_ELEMS;

    k_all<<<TOKS / 32, 512, 0, stream>>>(h, prev, query, score_w, out_w, tg_w,
                                         gate, tg_b, qnw, Wd, Wu, out, alpha);
}

// Round 11
// 79.465 us; speedup vs baseline: 1.4890x; 1.0609x over previous
//
#include <hip/hip_runtime.h>
#include <hip/hip_bf16.h>

#define D_DIM 1024
#define L_DIM 8
#define T_DIM 2048
#define B_DIM 4
#define TOKS  (B_DIM * T_DIM)                 // 8192
#define OUT_ELEMS ((size_t)TOKS * D_DIM)      // 8388608
#define EPSF 1e-6f

typedef __attribute__((ext_vector_type(8)))  short short8_t;
typedef __attribute__((ext_vector_type(16))) float f32x16_t;
typedef __attribute__((ext_vector_type(4)))  float f32x4_t;

__device__ __forceinline__ float dot4v(const f32x4_t& a, const f32x4_t& b) {
    return a.x * b.x + a.y * b.y + a.z * b.z + a.w * b.w;
}

__device__ __forceinline__ unsigned short f2bf(float f) {
    union { __hip_bfloat16 h; unsigned short u; } x;
    x.h = __float2bfloat16(f);
    return x.u;
}

__device__ __forceinline__ float bf2f(unsigned short u) {
    union { unsigned int i; float f; } x;
    x.i = ((unsigned int)u) << 16;
    return x.f;
}

// ---------------------------------------------------------------------------
// Single fused kernel. 256 blocks x 512 threads; block = 32 tokens.
// Phase A (one barrier chain): q tile via MFMA GEMM1/GEMM2 -> qt LDS (bf16).
// Phase B (ZERO barriers): wave-per-token x4; prev rows in registers (PLAIN
//   loads -> allow L3 retention across graph replays), butterflies in-wave,
//   softmax, delta, rmsnorm, gated residual, nt out store.
// ---------------------------------------------------------------------------
__global__ __launch_bounds__(512) void k_all(const float* __restrict__ h,
                                             const float* __restrict__ prev,
                                             const float* __restrict__ query,
                                             const float* __restrict__ score_w,
                                             const float* __restrict__ out_w,
                                             const float* __restrict__ tg_w,
                                             const float* __restrict__ gate,
                                             const float* __restrict__ tg_b,
                                             const float* __restrict__ qnw,
                                             const float* __restrict__ Wd,
                                             const float* __restrict__ Wu,
                                             float* __restrict__ out,
                                             float* __restrict__ alpha_out) {
    __shared__ __align__(16) char smem[65536];                 // c_red | qt overlay
    float (*c_red)[2][16][64] = (float (*)[2][16][64])smem;    // 64 KB
    unsigned short* qt = (unsigned short*)smem;                // 32 x 1024 bf16

    __shared__ float ssq_red[8][32];
    __shared__ float scale_sh[32];
    __shared__ unsigned short r_sw[2048];

    int tid  = threadIdx.x;
    int w    = tid >> 6;
    int lane = tid & 63;
    int t0   = blockIdx.x * 32;

    // ================= Phase A: GEMM1 =================
    f32x16_t acc0, acc1;
#pragma unroll
    for (int r = 0; r < 16; ++r) { acc0[r] = 0.f; acc1[r] = 0.f; }

    int arow = lane & 31;
    int koff = w * 128 + (lane >> 5) * 8;
    const float* hrow = h + (size_t)(t0 + arow) * D_DIM + koff;
    const float* w0r  = Wd + (size_t)arow * D_DIM + koff;
    const float* w1r  = Wd + (size_t)(32 + arow) * D_DIM + koff;
    const float* nr   = qnw + koff;

    float ssq = 0.f;
#pragma unroll
    for (int s = 0; s < 8; ++s) {
        f32x4_t ha = *(const f32x4_t*)(hrow + s * 16);
        f32x4_t hb = *(const f32x4_t*)(hrow + s * 16 + 4);
        ssq += dot4v(ha, ha) + dot4v(hb, hb);
        short8_t af;
        af[0] = (short)f2bf(ha.x); af[1] = (short)f2bf(ha.y);
        af[2] = (short)f2bf(ha.z); af[3] = (short)f2bf(ha.w);
        af[4] = (short)f2bf(hb.x); af[5] = (short)f2bf(hb.y);
        af[6] = (short)f2bf(hb.z); af[7] = (short)f2bf(hb.w);
        f32x4_t na = *(const f32x4_t*)(nr + s * 16);
        f32x4_t nb = *(const f32x4_t*)(nr + s * 16 + 4);
        f32x4_t wa = *(const f32x4_t*)(w0r + s * 16);
        f32x4_t wb = *(const f32x4_t*)(w0r + s * 16 + 4);
        short8_t bf0;
        bf0[0] = (short)f2bf(wa.x * na.x); bf0[1] = (short)f2bf(wa.y * na.y);
        bf0[2] = (short)f2bf(wa.z * na.z); bf0[3] = (short)f2bf(wa.w * na.w);
        bf0[4] = (short)f2bf(wb.x * nb.x); bf0[5] = (short)f2bf(wb.y * nb.y);
        bf0[6] = (short)f2bf(wb.z * nb.z); bf0[7] = (short)f2bf(wb.w * nb.w);
        f32x4_t va = *(const f32x4_t*)(w1r + s * 16);
        f32x4_t vb = *(const f32x4_t*)(w1r + s * 16 + 4);
        short8_t bf1;
        bf1[0] = (short)f2bf(va.x * na.x); bf1[1] = (short)f2bf(va.y * na.y);
        bf1[2] = (short)f2bf(va.z * na.z); bf1[3] = (short)f2bf(va.w * na.w);
        bf1[4] = (short)f2bf(vb.x * nb.x); bf1[5] = (short)f2bf(vb.y * nb.y);
        bf1[6] = (short)f2bf(vb.z * nb.z); bf1[7] = (short)f2bf(vb.w * nb.w);
        acc0 = __builtin_amdgcn_mfma_f32_32x32x16_bf16(af, bf0, acc0, 0, 0, 0);
        acc1 = __builtin_amdgcn_mfma_f32_32x32x16_bf16(af, bf1, acc1, 0, 0, 0);
    }

    ssq += __shfl_xor(ssq, 32, 64);
    if (lane < 32) ssq_red[w][lane] = ssq;
#pragma unroll
    for (int r = 0; r < 16; ++r) {
        c_red[w][0][r][lane] = acc0[r];
        c_red[w][1][r][lane] = acc1[r];
    }
    __syncthreads();

    if (tid < 32) {
        float s8 = 0.f;
#pragma unroll
        for (int u = 0; u < 8; ++u) s8 += ssq_red[u][tid];
        scale_sh[tid] = rsqrtf(s8 * (1.f / D_DIM) + EPSF);
    }
    __syncthreads();

    // pack r tile: sum 8 K-partials, scale, bf16, XOR-swizzle store
    for (int idx = tid; idx < 2048; idx += 512) {
        int nj = idx >> 10, rem = idx & 1023, reg = rem >> 6, ln = rem & 63;
        float v = 0.f;
#pragma unroll
        for (int u = 0; u < 8; ++u) v += c_red[u][nj][reg][ln];
        int tk = (reg & 3) + 8 * (reg >> 2) + 4 * (ln >> 5);
        int j  = nj * 32 + (ln & 31);
        v *= scale_sh[tk];
        int byte = (tk * 128 + j * 2) ^ ((tk & 7) << 4);
        r_sw[byte >> 1] = f2bf(v);
    }
    __syncthreads();

    // ================= Phase A: GEMM2 -> qt =================
    short8_t afr[4];
#pragma unroll
    for (int s = 0; s < 4; ++s) {
        int tk = lane & 31;
        int k  = s * 16 + (lane >> 5) * 8;
        int byte = (tk * 128 + k * 2) ^ ((tk & 7) << 4);
        afr[s] = *(const short8_t*)(&r_sw[byte >> 1]);
    }
    __syncthreads();   // c_red dead -> qt overlay safe

#pragma unroll
    for (int i = 0; i < 4; ++i) {
        int n0 = (w * 4 + i) * 32;
        int d  = n0 + (lane & 31);
        f32x16_t c;
#pragma unroll
        for (int r = 0; r < 16; ++r) c[r] = 0.f;
        const float* wup = Wu + (size_t)d * 64 + (lane >> 5) * 8;
#pragma unroll
        for (int s = 0; s < 4; ++s) {
            f32x4_t ua = *(const f32x4_t*)(wup + s * 16);
            f32x4_t ub = *(const f32x4_t*)(wup + s * 16 + 4);
            short8_t bf;
            bf[0] = (short)f2bf(ua.x); bf[1] = (short)f2bf(ua.y);
            bf[2] = (short)f2bf(ua.z); bf[3] = (short)f2bf(ua.w);
            bf[4] = (short)f2bf(ub.x); bf[5] = (short)f2bf(ub.y);
            bf[6] = (short)f2bf(ub.z); bf[7] = (short)f2bf(ub.w);
            c = __builtin_amdgcn_mfma_f32_32x32x16_bf16(afr[s], bf, c, 0, 0, 0);
        }
        float qd  = query[d];
        float swd = score_w[d];
#pragma unroll
        for (int r = 0; r < 16; ++r) {
            int tk = (r & 3) + 8 * (r >> 2) + 4 * (lane >> 5);
            unsigned int v = f2bf((qd + c[r]) * swd);
            unsigned int pv = (unsigned int)__shfl_xor((int)v, 1, 64);
            if ((lane & 1) == 0) {
                unsigned int word = (v & 0xffffu) | (pv << 16);
                *(unsigned int*)&qt[tk * 1024 + d] = word;
            }
        }
    }
    __syncthreads();   // qt ready; NO MORE BARRIERS below

    // ================= Phase B: wave-per-token, zero barriers =============
    int bb    = t0 >> 11;
    int tloc0 = t0 & (T_DIM - 1);

#pragma unroll 1
    for (int i = 0; i < 4; ++i) {
        int tt  = w * 4 + i;              // local token 0..31
        int tok = t0 + tt;
        int t   = tloc0 + tt;

        const float* pb = prev + ((size_t)(bb * L_DIM) * T_DIM + t) * D_DIM + lane * 4;
        f32x4_t p[L_DIM][4];
#pragma unroll
        for (int l = 0; l < L_DIM; ++l)
#pragma unroll
            for (int c = 0; c < 4; ++c)
                p[l][c] = *(const f32x4_t*)(pb + (size_t)l * T_DIM * D_DIM + c * 256);

        const float* hb = h + (size_t)tok * D_DIM + lane * 4;
        f32x4_t h4[4], qv[4];
#pragma unroll
        for (int c = 0; c < 4; ++c) h4[c] = *(const f32x4_t*)(hb + c * 256);
#pragma unroll
        for (int c = 0; c < 4; ++c) {
            short4 qr = *(const short4*)&qt[tt * 1024 + c * 256 + lane * 4];
            qv[c].x = bf2f((unsigned short)qr.x);
            qv[c].y = bf2f((unsigned short)qr.y);
            qv[c].z = bf2f((unsigned short)qr.z);
            qv[c].w = bf2f((unsigned short)qr.w);
        }

        float tgp = 0.f;
#pragma unroll
        for (int c = 0; c < 4; ++c) {
            f32x4_t tw = *(const f32x4_t*)(tg_w + c * 256 + lane * 4);
            tgp += dot4v(h4[c], tw);
        }

        float ss[L_DIM], dt[L_DIM];
#pragma unroll
        for (int l = 0; l < L_DIM; ++l) {
            float s = 0.f, d = 0.f;
#pragma unroll
            for (int c = 0; c < 4; ++c) {
                s += dot4v(p[l][c], p[l][c]);
                d += dot4v(p[l][c], qv[c]);
            }
            ss[l] = s; dt[l] = d;
        }

#pragma unroll
        for (int off = 32; off; off >>= 1) {
#pragma unroll
            for (int l = 0; l < L_DIM; ++l) {
                ss[l] += __shfl_xor(ss[l], off, 64);
                dt[l] += __shfl_xor(dt[l], off, 64);
            }
            tgp += __shfl_xor(tgp, off, 64);
        }

        float al[L_DIM], mx = -1e30f;
#pragma unroll
        for (int l = 0; l < L_DIM; ++l) {
            al[l] = dt[l] * rsqrtf(ss[l] * (1.f / D_DIM) + EPSF);
            mx = fmaxf(mx, al[l]);
        }
        float asum = 0.f;
#pragma unroll
        for (int l = 0; l < L_DIM; ++l) { al[l] = __expf(al[l] - mx); asum += al[l]; }
        float inv = 1.f / asum;
#pragma unroll
        for (int l = 0; l < L_DIM; ++l) al[l] *= inv;

        float g = gate[0] / (1.f + __expf(-(tgp + tg_b[0])));

        f32x4_t dl[4];
#pragma unroll
        for (int c = 0; c < 4; ++c) { dl[c].x = 0.f; dl[c].y = 0.f; dl[c].z = 0.f; dl[c].w = 0.f; }
#pragma unroll
        for (int l = 0; l < L_DIM; ++l)
#pragma unroll
            for (int c = 0; c < 4; ++c) {
                dl[c].x += al[l] * p[l][c].x;
                dl[c].y += al[l] * p[l][c].y;
                dl[c].z += al[l] * p[l][c].z;
                dl[c].w += al[l] * p[l][c].w;
            }

        float dss = 0.f;
#pragma unroll
        for (int c = 0; c < 4; ++c) dss += dot4v(dl[c], dl[c]);
#pragma unroll
        for (int off = 32; off; off >>= 1) dss += __shfl_xor(dss, off, 64);
        float dscale = rsqrtf(dss * (1.f / D_DIM) + EPSF);

        float* ob = out + (size_t)tok * D_DIM + lane * 4;
#pragma unroll
        for (int c = 0; c < 4; ++c) {
            f32x4_t ow = *(const f32x4_t*)(out_w + c * 256 + lane * 4);
            f32x4_t o;
            o.x = h4[c].x + g * dl[c].x * dscale * ow.x;
            o.y = h4[c].y + g * dl[c].y * dscale * ow.y;
            o.z = h4[c].z + g * dl[c].z * dscale * ow.z;
            o.w = h4[c].w + g * dl[c].w * dscale * ow.w;
            __builtin_nontemporal_store(o, (f32x4_t*)(ob + c * 256));
        }

        if (lane < L_DIM)
            alpha_out[(size_t)bb * (L_DIM * T_DIM) + (size_t)lane * T_DIM + t] = al[lane];
    }
}

extern "C" void kernel_launch(void* const* d_in, const int* in_sizes, int n_in,
                              void* d_out, int out_size, void* d_ws, size_t ws_size,
                              hipStream_t stream) {
    (void)in_sizes; (void)n_in; (void)out_size; (void)d_ws; (void)ws_size;
    const float* h       = (const float*)d_in[0];
    const float* prev    = (const float*)d_in[1];
    const float* query   = (const float*)d_in[2];
    const float* gate    = (const float*)d_in[3];
    const float* score_w = (const float*)d_in[4];
    const float* out_w   = (const float*)d_in[5];
    const float* qnw     = (const float*)d_in[6];
    const float* Wd      = (const float*)d_in[7];
    const float* Wu      = (const float*)d_in[8];
    const float* tg_w    = (const float*)d_in[9];
    const float* tg_b    = (const float*)d_in[10];

    float* out   = (float*)d_out;
    float* alpha = out + OUT_ELEMS;

    k_all<<<TOKS / 32, 512, 0, stream>>>(h, prev, query, score_w, out_w, tg_w,
                                         gate, tg_b, qnw, Wd, Wu, out, alpha);
}